// Round 1
// baseline (4133.992 us; speedup 1.0000x reference)
//
#include <hip/hip_runtime.h>

// HyperGraphLayer: D=64 fixed.
//
// Pipeline:
//  K0 zero_f4      : zero all of d_out (node_weight accum lives in d_out[0:N*64],
//                    agg accum lives in d_out[N*64:...])
//  K1 hedge_pre    : gate = sigmoid(hedge@Wg+bg), hwh = hedge@Wh          -> ws
//  K2 inc_scatter  : node_weight[inc_node[e]] += gate[inc_hedge[e]]      (atomics)
//  K3 node_update  : nn = tanh((node@Wn+bn)*node_weight) -> d_out (in place);
//                    nv = sigmoid(nn@Wv)                                  -> ws
//  K4 adj_scatter  : agg[adj_dst[e]] += hwh[adj_src[e]] * nv[adj_node[e]] (atomics)
//  K5 hedge_final  : out_hedge = tanh(hedge@Ws + agg + bh)  (in place on d_out)
//
// GEMM kernels: wave-per-row, lane = output column, W column register-cached
// (64 VGPR per matrix), row broadcast via wave-synchronous LDS float4 reads.

#define WPB 4  // waves per block (256 threads)

__device__ __forceinline__ float sigmoidf_(float x) { return 1.0f / (1.0f + __expf(-x)); }

__global__ void zero_f4(float4* __restrict__ p, long n4) {
  long i = (long)blockIdx.x * blockDim.x + threadIdx.x;
  long st = (long)gridDim.x * blockDim.x;
  for (; i < n4; i += st) p[i] = make_float4(0.f, 0.f, 0.f, 0.f);
}

__global__ __launch_bounds__(256, 2) void hedge_pre(
    const float* __restrict__ hedge, const float* __restrict__ Wg,
    const float* __restrict__ bg, const float* __restrict__ Wh,
    float* __restrict__ gate, float* __restrict__ hwh, int H) {
  __shared__ __align__(16) float rowbuf[WPB][64];
  const int lane = threadIdx.x & 63;
  const int wv = threadIdx.x >> 6;
  float wg[64], wh[64];
#pragma unroll
  for (int k = 0; k < 64; k++) { wg[k] = Wg[k * 64 + lane]; wh[k] = Wh[k * 64 + lane]; }
  const float bgl = bg[lane];
  const int gw0 = blockIdx.x * WPB + wv;
  const int gws = gridDim.x * WPB;
  for (int r = gw0; r < H; r += gws) {
    rowbuf[wv][lane] = hedge[(long)r * 64 + lane];
    const float4* rb = (const float4*)rowbuf[wv];
    float ag = 0.f, ah = 0.f;
#pragma unroll
    for (int k0 = 0; k0 < 16; k0++) {
      float4 r4 = rb[k0];
      const float rr[4] = {r4.x, r4.y, r4.z, r4.w};
#pragma unroll
      for (int j = 0; j < 4; j++) {
        ag = fmaf(rr[j], wg[4 * k0 + j], ag);
        ah = fmaf(rr[j], wh[4 * k0 + j], ah);
      }
    }
    gate[(long)r * 64 + lane] = sigmoidf_(ag + bgl);
    hwh[(long)r * 64 + lane] = ah;
  }
}

__global__ void inc_scatter(const int* __restrict__ inode, const int* __restrict__ ihedge,
                            const float4* __restrict__ gate4, float* __restrict__ nw, long n) {
  long i = (long)blockIdx.x * blockDim.x + threadIdx.x;
  long st = (long)gridDim.x * blockDim.x;
  for (; i < n; i += st) {
    int e = (int)(i >> 4), q = (int)(i & 15);
    int gh = ihedge[e], gn = inode[e];
    float4 g = gate4[(long)gh * 16 + q];
    float* dst = nw + (long)gn * 64 + q * 4;
    atomicAdd(dst + 0, g.x);
    atomicAdd(dst + 1, g.y);
    atomicAdd(dst + 2, g.z);
    atomicAdd(dst + 3, g.w);
  }
}

__global__ __launch_bounds__(256, 2) void node_update(
    const float* __restrict__ node, const float* __restrict__ Wn,
    const float* __restrict__ bn, const float* __restrict__ Wv,
    float* __restrict__ nnio /* in: node_weight, out: new_node */,
    float* __restrict__ nv, int N) {
  __shared__ __align__(16) float rowbuf[WPB][64];
  const int lane = threadIdx.x & 63;
  const int wv = threadIdx.x >> 6;
  float wn[64], wvv[64];
#pragma unroll
  for (int k = 0; k < 64; k++) { wn[k] = Wn[k * 64 + lane]; wvv[k] = Wv[k * 64 + lane]; }
  const float bnl = bn[lane];
  const int gw0 = blockIdx.x * WPB + wv;
  const int gws = gridDim.x * WPB;
  for (int r = gw0; r < N; r += gws) {
    rowbuf[wv][lane] = node[(long)r * 64 + lane];
    const float w = nnio[(long)r * 64 + lane];
    const float4* rb = (const float4*)rowbuf[wv];
    float t = 0.f;
#pragma unroll
    for (int k0 = 0; k0 < 16; k0++) {
      float4 r4 = rb[k0];
      const float rr[4] = {r4.x, r4.y, r4.z, r4.w};
#pragma unroll
      for (int j = 0; j < 4; j++) t = fmaf(rr[j], wn[4 * k0 + j], t);
    }
    float nn = tanhf((t + bnl) * w);
    nnio[(long)r * 64 + lane] = nn;
    rowbuf[wv][lane] = nn;  // second broadcast phase (DS ops are in-order per wave)
    float s = 0.f;
#pragma unroll
    for (int k0 = 0; k0 < 16; k0++) {
      float4 r4 = rb[k0];
      const float rr[4] = {r4.x, r4.y, r4.z, r4.w};
#pragma unroll
      for (int j = 0; j < 4; j++) s = fmaf(rr[j], wvv[4 * k0 + j], s);
    }
    nv[(long)r * 64 + lane] = sigmoidf_(s);
  }
}

__global__ void adj_scatter(const int* __restrict__ dsti, const int* __restrict__ srci,
                            const int* __restrict__ nodei, const float4* __restrict__ hwh4,
                            const float4* __restrict__ nv4, float* __restrict__ agg, long n) {
  long i = (long)blockIdx.x * blockDim.x + threadIdx.x;
  long st = (long)gridDim.x * blockDim.x;
  for (; i < n; i += st) {
    int e = (int)(i >> 4), q = (int)(i & 15);
    int d0 = dsti[e], s0 = srci[e], n0 = nodei[e];
    float4 a = hwh4[(long)s0 * 16 + q];
    float4 b = nv4[(long)n0 * 16 + q];
    float* dp = agg + (long)d0 * 64 + q * 4;
    atomicAdd(dp + 0, a.x * b.x);
    atomicAdd(dp + 1, a.y * b.y);
    atomicAdd(dp + 2, a.z * b.z);
    atomicAdd(dp + 3, a.w * b.w);
  }
}

__global__ __launch_bounds__(256, 2) void hedge_final(
    const float* __restrict__ hedge, const float* __restrict__ Ws,
    const float* __restrict__ bh, float* __restrict__ hio /* in: agg, out: result */, int H) {
  __shared__ __align__(16) float rowbuf[WPB][64];
  const int lane = threadIdx.x & 63;
  const int wv = threadIdx.x >> 6;
  float wsr[64];
#pragma unroll
  for (int k = 0; k < 64; k++) wsr[k] = Ws[k * 64 + lane];
  const float bhl = bh[lane];
  const int gw0 = blockIdx.x * WPB + wv;
  const int gws = gridDim.x * WPB;
  for (int r = gw0; r < H; r += gws) {
    rowbuf[wv][lane] = hedge[(long)r * 64 + lane];
    const float4* rb = (const float4*)rowbuf[wv];
    float s = 0.f;
#pragma unroll
    for (int k0 = 0; k0 < 16; k0++) {
      float4 r4 = rb[k0];
      const float rr[4] = {r4.x, r4.y, r4.z, r4.w};
#pragma unroll
      for (int j = 0; j < 4; j++) s = fmaf(rr[j], wsr[4 * k0 + j], s);
    }
    const float a = hio[(long)r * 64 + lane];
    hio[(long)r * 64 + lane] = tanhf(s + a + bhl);
  }
}

extern "C" void kernel_launch(void* const* d_in, const int* in_sizes, int n_in,
                              void* d_out, int out_size, void* d_ws, size_t ws_size,
                              hipStream_t stream) {
  const float* node = (const float*)d_in[0];
  const float* hedge = (const float*)d_in[1];
  const int* inc_node = (const int*)d_in[2];
  const int* inc_hedge = (const int*)d_in[3];
  const int* adj_dst = (const int*)d_in[4];
  const int* adj_src = (const int*)d_in[5];
  const int* adj_node = (const int*)d_in[6];
  const float* Wg = (const float*)d_in[7];
  const float* bg = (const float*)d_in[8];
  const float* Wn = (const float*)d_in[9];
  const float* bn = (const float*)d_in[10];
  const float* Wh = (const float*)d_in[11];
  const float* Wv = (const float*)d_in[12];
  const float* Ws = (const float*)d_in[13];
  const float* bh = (const float*)d_in[14];

  const int N = in_sizes[0] / 64;
  const int H = in_sizes[1] / 64;
  const int NINC = in_sizes[2];
  const int NADJ = in_sizes[4];

  float* out_nn = (float*)d_out;                  // node_weight accum -> new_node
  float* out_h = (float*)d_out + (size_t)N * 64;  // agg accum -> new_hedge

  // workspace: gate[H*64] | hwh[H*64] | nv[N*64]  (all f32) = 230.4 MB
  float* ws_gate = (float*)d_ws;
  float* ws_hwh = ws_gate + (size_t)H * 64;
  float* ws_nv = ws_hwh + (size_t)H * 64;

  zero_f4<<<2048, 256, 0, stream>>>((float4*)d_out, (long)out_size / 4);
  hedge_pre<<<1024, 256, 0, stream>>>(hedge, Wg, bg, Wh, ws_gate, ws_hwh, H);
  inc_scatter<<<8192, 256, 0, stream>>>(inc_node, inc_hedge, (const float4*)ws_gate,
                                        out_nn, (long)NINC * 16);
  node_update<<<2048, 256, 0, stream>>>(node, Wn, bn, Wv, out_nn, ws_nv, N);
  adj_scatter<<<8192, 256, 0, stream>>>(adj_dst, adj_src, adj_node, (const float4*)ws_hwh,
                                        (const float4*)ws_nv, out_h, (long)NADJ * 16);
  hedge_final<<<1024, 256, 0, stream>>>(hedge, Ws, bh, out_h, H);
}

// Round 2
// 1704.621 us; speedup vs baseline: 2.4252x; 2.4252x over previous
//
#include <hip/hip_runtime.h>

// HyperGraphLayer, D=64. Sort-based (counting-sort CSR) segment sums fused
// into the consuming GEMMs — zero f32 atomics.
//
// Pipeline:
//  zero_i4     : zero inc_pos[N] + adj_pos[H] (contiguous)
//  hedge_pre   : gate = sigmoid(hedge@Wg+bg), hwh = hedge@Wh          -> ws
//  hist_k x2   : inc_pos[inc_node[e]]++ ; adj_pos[adj_dst[e]]++      (int atomics)
//  scan_*  x2  : exclusive prefix sum (block scan + top scan + add)
//  scat1/scat2 : position scatter -> sorted payloads (int atomics)
//                (after this, pos[r] == segment end; start = pos[r-1])
//  node_fused  : w = seg-sum(gate); nn = tanh((node@Wn+bn)*w) -> d_out;
//                nv = sigmoid(nn@Wv) -> ws
//  hedge_fused : agg = seg-sum(hwh[src]*nv[node]);
//                out = tanh(hedge@Ws + agg + bh) -> d_out
//
// GEMMs: wave-per-row, lane = out column, W columns register-cached,
// row broadcast via wave-synchronous LDS float4 reads (DS in-order per wave).

#define WPB 4  // waves per block (256 threads)

__device__ __forceinline__ float sigmoidf_(float x) { return 1.0f / (1.0f + __expf(-x)); }

__device__ __forceinline__ float dot64(const float4* __restrict__ rb, const float* wcol) {
  float acc = 0.f;
#pragma unroll
  for (int k0 = 0; k0 < 16; k0++) {
    float4 r4 = rb[k0];
    acc = fmaf(r4.x, wcol[4 * k0 + 0], acc);
    acc = fmaf(r4.y, wcol[4 * k0 + 1], acc);
    acc = fmaf(r4.z, wcol[4 * k0 + 2], acc);
    acc = fmaf(r4.w, wcol[4 * k0 + 3], acc);
  }
  return acc;
}

__global__ void zero_i4(int4* __restrict__ p, long n4) {
  long i = (long)blockIdx.x * blockDim.x + threadIdx.x;
  long st = (long)gridDim.x * blockDim.x;
  for (; i < n4; i += st) p[i] = make_int4(0, 0, 0, 0);
}

__global__ void hist_k(const int* __restrict__ idx, int* __restrict__ cnt, int n) {
  int i = blockIdx.x * blockDim.x + threadIdx.x;
  int st = gridDim.x * blockDim.x;
  for (; i < n; i += st) atomicAdd(&cnt[idx[i]], 1);
}

// per-block (1024 elems) in-place exclusive scan + block sums
__global__ void scan_blocks(int* __restrict__ d, int n, int* __restrict__ bsum) {
  __shared__ int s[256];
  const int b = blockIdx.x, t = threadIdx.x;
  const int i0 = b * 1024 + t * 4;
  int x[4];
  int sum = 0;
#pragma unroll
  for (int j = 0; j < 4; j++) {
    x[j] = (i0 + j < n) ? d[i0 + j] : 0;
    sum += x[j];
  }
  s[t] = sum;
  __syncthreads();
  for (int off = 1; off < 256; off <<= 1) {
    int v = (t >= off) ? s[t - off] : 0;
    __syncthreads();
    s[t] += v;
    __syncthreads();
  }
  if (t == 255) bsum[b] = s[255];
  int run = (t == 0) ? 0 : s[t - 1];
#pragma unroll
  for (int j = 0; j < 4; j++) {
    if (i0 + j < n) d[i0 + j] = run;
    run += x[j];
  }
}

// single-block exclusive scan of block sums (nb <= 1024)
__global__ void scan_top(int* __restrict__ b, int nb) {
  __shared__ int s[1024];
  const int t = threadIdx.x;
  s[t] = (t < nb) ? b[t] : 0;
  __syncthreads();
  for (int off = 1; off < 1024; off <<= 1) {
    int v = (t >= off) ? s[t - off] : 0;
    __syncthreads();
    s[t] += v;
    __syncthreads();
  }
  if (t < nb) b[t] = (t == 0) ? 0 : s[t - 1];
}

__global__ void scan_add(int* __restrict__ d, int n, const int* __restrict__ bsum) {
  int i = blockIdx.x * blockDim.x + threadIdx.x;
  if (i < n) d[i] += bsum[i >> 10];
}

__global__ void scat1(const int* __restrict__ key, const int* __restrict__ val,
                      int* __restrict__ pos, int* __restrict__ sval, int n) {
  int i = blockIdx.x * blockDim.x + threadIdx.x;
  int st = gridDim.x * blockDim.x;
  for (; i < n; i += st) {
    int p = atomicAdd(&pos[key[i]], 1);
    sval[p] = val[i];
  }
}

__global__ void scat2(const int* __restrict__ key, const int* __restrict__ v1,
                      const int* __restrict__ v2, int* __restrict__ pos,
                      int* __restrict__ s1, int* __restrict__ s2, int n) {
  int i = blockIdx.x * blockDim.x + threadIdx.x;
  int st = gridDim.x * blockDim.x;
  for (; i < n; i += st) {
    int p = atomicAdd(&pos[key[i]], 1);
    s1[p] = v1[i];
    s2[p] = v2[i];
  }
}

__global__ __launch_bounds__(256, 2) void hedge_pre(
    const float* __restrict__ hedge, const float* __restrict__ Wg,
    const float* __restrict__ bg, const float* __restrict__ Wh,
    float* __restrict__ gate, float* __restrict__ hwh, int H) {
  __shared__ __align__(16) float rowbuf[WPB][64];
  const int lane = threadIdx.x & 63;
  const int wv = threadIdx.x >> 6;
  float wg[64], wh[64];
#pragma unroll
  for (int k = 0; k < 64; k++) { wg[k] = Wg[k * 64 + lane]; wh[k] = Wh[k * 64 + lane]; }
  const float bgl = bg[lane];
  const int gw0 = blockIdx.x * WPB + wv;
  const int gws = gridDim.x * WPB;
  for (int r = gw0; r < H; r += gws) {
    rowbuf[wv][lane] = hedge[(long)r * 64 + lane];
    const float4* rb = (const float4*)rowbuf[wv];
    float ag = dot64(rb, wg);
    float ah = dot64(rb, wh);
    gate[(long)r * 64 + lane] = sigmoidf_(ag + bgl);
    hwh[(long)r * 64 + lane] = ah;
  }
}

__global__ __launch_bounds__(256, 2) void node_fused(
    const float* __restrict__ node, const float* __restrict__ Wn,
    const float* __restrict__ bn, const float* __restrict__ Wv,
    const int* __restrict__ pos, const int* __restrict__ sh,
    const float* __restrict__ gate, float* __restrict__ out_nn,
    float* __restrict__ nv, int N) {
  __shared__ __align__(16) float rowbuf[WPB][64];
  const int lane = threadIdx.x & 63;
  const int wv = threadIdx.x >> 6;
  float wn[64], wvv[64];
#pragma unroll
  for (int k = 0; k < 64; k++) { wn[k] = Wn[k * 64 + lane]; wvv[k] = Wv[k * 64 + lane]; }
  const float bnl = bn[lane];
  const int gw0 = blockIdx.x * WPB + wv;
  const int gws = gridDim.x * WPB;
  for (int r = gw0; r < N; r += gws) {
    rowbuf[wv][lane] = node[(long)r * 64 + lane];  // issue early; consumed after gathers
    const int start = (r == 0) ? 0 : pos[r - 1];
    const int end = pos[r];
    float w = 0.f;
    int p = start;
    for (; p + 1 < end; p += 2) {
      int h0 = __builtin_amdgcn_readfirstlane(sh[p]);
      int h1 = __builtin_amdgcn_readfirstlane(sh[p + 1]);
      w += gate[(long)h0 * 64 + lane] + gate[(long)h1 * 64 + lane];
    }
    if (p < end) {
      int h0 = __builtin_amdgcn_readfirstlane(sh[p]);
      w += gate[(long)h0 * 64 + lane];
    }
    const float4* rb = (const float4*)rowbuf[wv];
    float t = dot64(rb, wn);
    float nn = tanhf((t + bnl) * w);
    out_nn[(long)r * 64 + lane] = nn;
    rowbuf[wv][lane] = nn;  // DS ops in-order per wave
    float s = dot64(rb, wvv);
    nv[(long)r * 64 + lane] = sigmoidf_(s);
  }
}

__global__ __launch_bounds__(256, 4) void hedge_fused(
    const float* __restrict__ hedge, const float* __restrict__ Ws,
    const float* __restrict__ bh, const int* __restrict__ pos,
    const int* __restrict__ ssrc, const int* __restrict__ snode,
    const float* __restrict__ hwh, const float* __restrict__ nv,
    float* __restrict__ out_h, int H) {
  __shared__ __align__(16) float rowbuf[WPB][64];
  const int lane = threadIdx.x & 63;
  const int wv = threadIdx.x >> 6;
  float wsr[64];
#pragma unroll
  for (int k = 0; k < 64; k++) wsr[k] = Ws[k * 64 + lane];
  const float bhl = bh[lane];
  const int gw0 = blockIdx.x * WPB + wv;
  const int gws = gridDim.x * WPB;
  for (int r = gw0; r < H; r += gws) {
    rowbuf[wv][lane] = hedge[(long)r * 64 + lane];
    const int start = (r == 0) ? 0 : pos[r - 1];
    const int end = pos[r];
    float acc = 0.f;
    int p = start;
    for (; p + 1 < end; p += 2) {
      int s0 = __builtin_amdgcn_readfirstlane(ssrc[p]);
      int n0 = __builtin_amdgcn_readfirstlane(snode[p]);
      int s1 = __builtin_amdgcn_readfirstlane(ssrc[p + 1]);
      int n1 = __builtin_amdgcn_readfirstlane(snode[p + 1]);
      acc += hwh[(long)s0 * 64 + lane] * nv[(long)n0 * 64 + lane];
      acc += hwh[(long)s1 * 64 + lane] * nv[(long)n1 * 64 + lane];
    }
    if (p < end) {
      int s0 = __builtin_amdgcn_readfirstlane(ssrc[p]);
      int n0 = __builtin_amdgcn_readfirstlane(snode[p]);
      acc += hwh[(long)s0 * 64 + lane] * nv[(long)n0 * 64 + lane];
    }
    const float4* rb = (const float4*)rowbuf[wv];
    float s = dot64(rb, wsr);
    out_h[(long)r * 64 + lane] = tanhf(s + acc + bhl);
  }
}

extern "C" void kernel_launch(void* const* d_in, const int* in_sizes, int n_in,
                              void* d_out, int out_size, void* d_ws, size_t ws_size,
                              hipStream_t stream) {
  const float* node = (const float*)d_in[0];
  const float* hedge = (const float*)d_in[1];
  const int* inc_node = (const int*)d_in[2];
  const int* inc_hedge = (const int*)d_in[3];
  const int* adj_dst = (const int*)d_in[4];
  const int* adj_src = (const int*)d_in[5];
  const int* adj_node = (const int*)d_in[6];
  const float* Wg = (const float*)d_in[7];
  const float* bg = (const float*)d_in[8];
  const float* Wn = (const float*)d_in[9];
  const float* bn = (const float*)d_in[10];
  const float* Wh = (const float*)d_in[11];
  const float* Wv = (const float*)d_in[12];
  const float* Ws = (const float*)d_in[13];
  const float* bh = (const float*)d_in[14];

  const int N = in_sizes[0] / 64;
  const int H = in_sizes[1] / 64;
  const int NINC = in_sizes[2];
  const int NADJ = in_sizes[4];

  float* out_nn = (float*)d_out;                  // new node features
  float* out_h = (float*)d_out + (size_t)N * 64;  // new hedge features

  // ws layout: gate[H*64] hwh[H*64] nv[N*64] inc_pos[N] adj_pos[H]
  //            adj_ssrc[NADJ] adj_snod[NADJ] bsumA[1024] bsumB[1024]  (~249 MB)
  float* ws_gate = (float*)d_ws;
  float* ws_hwh = ws_gate + (size_t)H * 64;
  float* ws_nv = ws_hwh + (size_t)H * 64;
  int* inc_pos = (int*)(ws_nv + (size_t)N * 64);
  int* adj_pos = inc_pos + N;
  int* adj_ssrc = adj_pos + H;
  int* adj_snod = adj_ssrc + NADJ;
  int* bsumA = adj_snod + NADJ;
  int* bsumB = bsumA + 1024;
  // inc sorted payload parked in the not-yet-written hedge half of d_out
  // (consumed by node_fused, which runs before hedge_fused writes out_h)
  int* inc_sorted = (int*)out_h;  // NINC ints = 8 MB <= 51.2 MB region

  const int nbA = (N + 1023) / 1024;  // blocks for node-side scan
  const int nbB = (H + 1023) / 1024;  // blocks for hedge-side scan

  zero_i4<<<256, 256, 0, stream>>>((int4*)inc_pos, (long)(N + H) / 4);
  hedge_pre<<<1024, 256, 0, stream>>>(hedge, Wg, bg, Wh, ws_gate, ws_hwh, H);
  hist_k<<<2048, 256, 0, stream>>>(inc_node, inc_pos, NINC);
  hist_k<<<2048, 256, 0, stream>>>(adj_dst, adj_pos, NADJ);
  scan_blocks<<<nbA, 256, 0, stream>>>(inc_pos, N, bsumA);
  scan_blocks<<<nbB, 256, 0, stream>>>(adj_pos, H, bsumB);
  scan_top<<<1, 1024, 0, stream>>>(bsumA, nbA);
  scan_top<<<1, 1024, 0, stream>>>(bsumB, nbB);
  scan_add<<<(N + 255) / 256, 256, 0, stream>>>(inc_pos, N, bsumA);
  scan_add<<<(H + 255) / 256, 256, 0, stream>>>(adj_pos, H, bsumB);
  scat1<<<2048, 256, 0, stream>>>(inc_node, inc_hedge, inc_pos, inc_sorted, NINC);
  scat2<<<2048, 256, 0, stream>>>(adj_dst, adj_src, adj_node, adj_pos, adj_ssrc, adj_snod, NADJ);
  node_fused<<<4096, 256, 0, stream>>>(node, Wn, bn, Wv, inc_pos, inc_sorted, ws_gate,
                                       out_nn, ws_nv, N);
  hedge_fused<<<2048, 256, 0, stream>>>(hedge, Ws, bh, adj_pos, adj_ssrc, adj_snod,
                                        ws_hwh, ws_nv, out_h, H);
}